// Round 7
// baseline (211.072 us; speedup 1.0000x reference)
//
#include <hip/hip_runtime.h>

// B=2, N=8192, K=10, I=3, LEN_IN=66. All buffers f32.
// LOCKED correctness recipe (R8-R12, passed, absmax 0.0625):
//   sq  = fmaf(z,z, fmaf(y,y, rn(x*x)))          (asc FMA)
//   dot = fmaf(z,z', fmaf(y,y', rn(x*x')))       (asc FMA)
//   d2  = fmaf(-2,dot, rn(sq_q + sq_c))          (== single-rounded sub form)
//   selection: strict <, stable lowest-index-first (lexicographic (d2,idx))
// R20: rendezvous threshold (atomic-free cross-wave pruning).
//   R16/R19 post-mortem: BOTH regressed by the same +126-128K VALU
//   cyc/SIMD. A ~15-inst publish tail can't do that; the DS atomic inside
//   flush() defeated the branch-skip over the TRIG check -> the ~115-inst
//   flush body issued (exec-masked) EVERY scan iteration: 128 it x ~115
//   inst x 2cyc = +29K/wave = +118K/SIMD. Matches. Rule: flush body stays
//   R13-pure (no atomics / convergent ops).
//   R20 keeps the pruning WITHOUT touching the hot path: two UNIFORM
//   rendezvous (after m=32 and m=128): flush; write d10 to thrS[wave][lane];
//   barrier; min-reduce 16 floats; nextafter-up (bit trick, once); freeze
//   in register thrR; trailing barrier (WAR safety for reuse). Flush's only
//   edit vs R13: `thr = fminf(d10, thrR)` (register-only, 1 inst).
//   Safety: blockmin of per-wave 11th-bests >= global 11th at all times;
//   nextafter-up makes the bound non-strict so d2-ties survive; pruned =>
//   strictly greater than global 11th => exact top-11 reaches the
//   unchanged merge. thrR init 3e38 => pass 1a is bit-identical to R13.
#define NPTS   8192
#define KNN    11
#define QPB    64          // queries per block (one per lane)
#define NTHR   1024
#define NSLICE 16          // candidate slices (one per wave)
#define SLEN   (NPTS / NSLICE)   // 512
#define DEPTH  10          // per-lane push-buffer entries (R13 value)
#define TRIG   7           // flush when any lane cnt >= TRIG (4 pushes headroom)
#define REND1  32          // rendezvous points (multiples of 4)
#define REND2  128

__global__ __launch_bounds__(NTHR, 4) void knn_mlp(
    const float* __restrict__ pos,
    const float* __restrict__ vel,
    const float* __restrict__ initc,
    const float* __restrict__ W1,
    const float* __restrict__ b1,
    const float* __restrict__ W2,
    const float* __restrict__ b2,
    const float* __restrict__ W3,
    const float* __restrict__ b3,
    float* __restrict__ out) {

    // Phased LDS (112KB + 4KB thrS):
    //   phase-scan : [0,32K) ssq | [32K,112K) push region [k][tid] u64
    //   phase-fold : [32K, ...) fold scratch (4.3KB)
    //   phase-merge: [0,45K) pd f32 | [45K,90K) pi i32   (ssq/region dead)
    __shared__ __align__(16) char smem[32 * 1024 + NTHR * DEPTH * 8];
    __shared__ float sW[405];           // Weff[396] + bias[6] + init[3]
    __shared__ float thrS[NSLICE][QPB]; // rendezvous scratch (4KB)

    float* ssq = (float*)smem;
    unsigned long long* region = (unsigned long long*)(smem + 32 * 1024);

    const int tid  = threadIdx.x;
    const int lane = tid & 63;
    const int wave = tid >> 6;
    const int b    = blockIdx.x >> 7;           // 128 blocks per batch
    const int n0   = (blockIdx.x & 127) * QPB;
    const int q    = n0 + lane;

    const float* posb = pos + b * NPTS * 3;
    const float* velb = vel + b * NPTS * 3;

    // ---- phase 1a: per-point sq into LDS (LOCKED recipe)
    for (int a = tid; a < NPTS; a += NTHR) {
        float x = posb[a * 3 + 0];
        float y = posb[a * 3 + 1];
        float z = posb[a * 3 + 2];
        ssq[a] = __fmaf_rn(z, z, __fmaf_rn(y, y, __fmul_rn(x, x)));
    }
    // ---- phase 1b: fold stage 1 (scratch in region): W12 = W1@W2, b12 = b1@W2+b2
    float* sW12 = (float*)region;
    for (int e = tid; e < 66 * 16; e += NTHR) {
        int r = e >> 4, c = e & 15;
        float s = 0.f;
        for (int j = 0; j < 32; ++j) s += W1[r * 32 + j] * W2[j * 16 + c];
        sW12[e] = s;
    }
    if (tid < 16) {
        float s = b2[tid];
        for (int j = 0; j < 32; ++j) s += b1[j] * W2[j * 16 + tid];
        sW12[66 * 16 + tid] = s;
    }
    if (tid < 3) sW[402 + tid] = initc[b * 3 + tid];
    __syncthreads();
    // ---- fold stage 2: Weff = W12@W3, bias = b12@W3 + b3
    for (int e = tid; e < 66 * 6; e += NTHR) {
        int r = e / 6, c = e - r * 6;
        float s = 0.f;
        for (int j = 0; j < 16; ++j) s += sW12[r * 16 + j] * W3[j * 6 + c];
        sW[e] = s;
    }
    if (tid < 6) {
        float s = b3[tid];
        for (int j = 0; j < 16; ++j) s += sW12[66 * 16 + j] * W3[j * 6 + tid];
        sW[396 + tid] = s;
    }
    __syncthreads();   // fold scratch done -> region becomes push buffers

    const float qx = posb[q * 3 + 0];
    const float qy = posb[q * 3 + 1];
    const float qz = posb[q * 3 + 2];
    const float sqq = ssq[q];           // identical bits to locked recipe

    // Top-11 in NAMED SCALARS (forced register residency; R12 demoted arrays).
    float d0 = 3.0e38f, d1 = 3.0e38f, d2v = 3.0e38f, d3 = 3.0e38f, d4 = 3.0e38f,
          d5 = 3.0e38f, d6 = 3.0e38f, d7 = 3.0e38f, d8 = 3.0e38f, d9 = 3.0e38f,
          d10 = 3.0e38f;
    int   i0 = 0x7FFFFFFF, i1 = 0x7FFFFFFF, i2v = 0x7FFFFFFF, i3 = 0x7FFFFFFF,
          i4 = 0x7FFFFFFF, i5 = 0x7FFFFFFF, i6 = 0x7FFFFFFF, i7 = 0x7FFFFFFF,
          i8 = 0x7FFFFFFF, i9 = 0x7FFFFFFF, i10 = 0x7FFFFFFF;

    float thrR = 3.0e38f;      // frozen rendezvous bound (register-only)
    float thr  = 3.0e38f;      // active bound; only over-buffers, never drops
    int cnt = 0;

    // Hand-unrolled stable insert (identical semantics to the array loop).
    auto insert = [&](float nd, int nj) {
        if (nd < d10) {
            bool c, cp;
            cp = nd < d9;  d10 = cp ? d9  : nd;             i10 = cp ? i9  : nj;             c = cp;
            cp = nd < d8;  d9  = cp ? d8  : (c ? nd : d9);  i9  = cp ? i8  : (c ? nj : i9);  c = cp;
            cp = nd < d7;  d8  = cp ? d7  : (c ? nd : d8);  i8  = cp ? i7  : (c ? nj : i8);  c = cp;
            cp = nd < d6;  d7  = cp ? d6  : (c ? nd : d7);  i7  = cp ? i6  : (c ? nj : i7);  c = cp;
            cp = nd < d5;  d6  = cp ? d5  : (c ? nd : d6);  i6  = cp ? i5  : (c ? nj : i6);  c = cp;
            cp = nd < d4;  d5  = cp ? d4  : (c ? nd : d5);  i5  = cp ? i4  : (c ? nj : i5);  c = cp;
            cp = nd < d3;  d4  = cp ? d3  : (c ? nd : d4);  i4  = cp ? i3  : (c ? nj : i4);  c = cp;
            cp = nd < d2v; d3  = cp ? d2v : (c ? nd : d3);  i3  = cp ? i2v : (c ? nj : i3);  c = cp;
            cp = nd < d1;  d2v = cp ? d1  : (c ? nd : d2v); i2v = cp ? i1  : (c ? nj : i2v); c = cp;
            cp = nd < d0;  d1  = cp ? d0  : (c ? nd : d1);  i1  = cp ? i0  : (c ? nj : i1);  c = cp;
            if (c) { d0 = nd; i0 = nj; }
        }
    };

    // R13-pure flush body: NO atomics / convergent ops (R19 lesson — a DS
    // atomic here defeats the branch-skip and issues this body every scan
    // iteration). Only edit vs R13: fminf with the register bound thrR.
    auto flush = [&]() {
#pragma unroll 1
        for (int k = 0; __any(k < cnt); ++k) {
            if (k < cnt) {
                unsigned long long e = region[k * NTHR + tid];  // [k][tid]: 2-way only
                float nd = __uint_as_float((unsigned)(e >> 32));
                int   nj = (int)(unsigned)(e & 0xFFFFFFFFull);
                insert(nd, nj);
            }
        }
        cnt = 0;
        thr = fminf(d10, thrR);
    };

    // Uniform rendezvous: tighten thrR from all 16 waves' current d10.
    auto rendezvous = [&]() {
        flush();
        thrS[wave][lane] = d10;
        __syncthreads();
        float bm = thrS[0][lane];
#pragma unroll
        for (int w = 1; w < NSLICE; ++w) bm = fminf(bm, thrS[w][lane]);
        __syncthreads();           // WAR: next rendezvous rewrites thrS
        // nextafter-up(bm) via order-preserving bit trick (once, ~8 inst):
        unsigned sb = __float_as_uint(bm);
        unsigned eb = (sb & 0x80000000u) ? ~sb : (sb | 0x80000000u);
        eb += 1u;
        float up = (eb & 0x80000000u) ? __uint_as_float(eb & 0x7FFFFFFFu)
                                      : __uint_as_float(~eb);
        thrR = fminf(thrR, up);
        thr  = fminf(d10, thrR);
    };

    auto proc = [&](float cx, float cy, float cz, float sqc, int j) {
        float dot = __fmaf_rn(qz, cz, __fmaf_rn(qy, cy, __fmul_rn(qx, cx)));
        float dd  = __fmaf_rn(-2.0f, dot, __fadd_rn(sqq, sqc)); // == rn(s-2dot)
        if (dd < thr) {
            region[cnt * NTHR + tid] =
                (((unsigned long long)__float_as_uint(dd)) << 32) | (unsigned)j;
            ++cnt;
        }
    };

    // ---- scan: wave streams its 512-candidate slice from global (L2-hot).
    // EXACT R13 loop body; split at REND1/REND2 for uniform rendezvous.
    const int base = wave * SLEN;
    const float4* gp = (const float4*)(posb + base * 3);  // 3 float4 per 4 cands
    const float4* sp = (const float4*)(ssq + base);
#pragma unroll 1
    for (int m = 0; m < REND1; m += 4) {
        int f = (m >> 2) * 3;
        float4 A = gp[f], Bv = gp[f + 1], C = gp[f + 2];
        float4 S = sp[m >> 2];
        int j = base + m;
        proc(A.x,  A.y,  A.z,  S.x, j + 0);
        proc(A.w,  Bv.x, Bv.y, S.y, j + 1);
        proc(Bv.z, Bv.w, C.x,  S.z, j + 2);
        proc(C.y,  C.z,  C.w,  S.w, j + 3);
        if (__any(cnt >= TRIG)) flush();                  // rare wave-uniform path
    }
    rendezvous();   // thr ~= rank-176-of-8192 bound
#pragma unroll 1
    for (int m = REND1; m < REND2; m += 4) {
        int f = (m >> 2) * 3;
        float4 A = gp[f], Bv = gp[f + 1], C = gp[f + 2];
        float4 S = sp[m >> 2];
        int j = base + m;
        proc(A.x,  A.y,  A.z,  S.x, j + 0);
        proc(A.w,  Bv.x, Bv.y, S.y, j + 1);
        proc(Bv.z, Bv.w, C.x,  S.z, j + 2);
        proc(C.y,  C.z,  C.w,  S.w, j + 3);
        if (__any(cnt >= TRIG)) flush();
    }
    rendezvous();   // thr ~= rank-44-of-8192 bound
#pragma unroll 1
    for (int m = REND2; m < SLEN; m += 4) {
        int f = (m >> 2) * 3;
        float4 A = gp[f], Bv = gp[f + 1], C = gp[f + 2];
        float4 S = sp[m >> 2];
        int j = base + m;
        proc(A.x,  A.y,  A.z,  S.x, j + 0);
        proc(A.w,  Bv.x, Bv.y, S.y, j + 1);
        proc(Bv.z, Bv.w, C.x,  S.z, j + 2);
        proc(C.y,  C.z,  C.w,  S.w, j + 3);
        if (__any(cnt >= TRIG)) flush();
    }
    flush();

    __syncthreads();   // scans done -> smem becomes merge lists
    float* pd = (float*)smem;                       // [NTHR][11] f32
    int*   pi = (int*)(smem + NTHR * KNN * 4);      // [NTHR][11] i32
    {
        float* pw = pd + tid * KNN;
        int*   iw = pi + tid * KNN;
        pw[0] = d0;  pw[1] = d1;  pw[2] = d2v; pw[3] = d3;  pw[4] = d4;
        pw[5] = d5;  pw[6] = d6;  pw[7] = d7;  pw[8] = d8;  pw[9] = d9;
        pw[10] = d10;
        iw[0] = i0;  iw[1] = i1;  iw[2] = i2v; iw[3] = i3;  iw[4] = i4;
        iw[5] = i5;  iw[6] = i6;  iw[7] = i7;  iw[8] = i8;  iw[9] = i9;
        iw[10] = i10;
    }
    __syncthreads();

    if (tid < QPB) {
        // 16-way merge, lexicographic (d2, idx) == global stable top-11.
        int p[NSLICE]; float hd[NSLICE]; int hi[NSLICE];
#pragma unroll
        for (int s = 0; s < NSLICE; ++s) {
            p[s]  = 0;
            hd[s] = pd[(s * 64 + tid) * KNN];
            hi[s] = pi[(s * 64 + tid) * KNN];
        }
        float acc[6];
#pragma unroll
        for (int c = 0; c < 6; ++c) acc[c] = sW[396 + c];

        for (int r = 0; r < KNN; ++r) {
            float bd = 3.9e38f; int bi = 0x7FFFFFFF; int bs = 0;
#pragma unroll
            for (int s = 0; s < NSLICE; ++s) {
                bool better = (hd[s] < bd) || (hd[s] == bd && hi[s] < bi);
                bs = better ? s : bs;
                bi = better ? hi[s] : bi;
                bd = better ? hd[s] : bd;
            }
            {   // advance winning slice head
                int pp = ++p[bs];
                if (pp < KNN) {
                    hd[bs] = pd[(bs * 64 + tid) * KNN + pp];
                    hi[bs] = pi[(bs * 64 + tid) * KNN + pp];
                } else { hd[bs] = 3.9e38f; hi[bs] = 0x7FFFFFFF; }
            }

            int bg = ((unsigned)bi < (unsigned)NPTS) ? bi : 0;   // defensive

            // velocity features: slots [r*3 .. r*3+2]
            const float* vp = velb + bg * 3;
            float vx = vp[0], vy = vp[1], vz = vp[2];
            const float* w = &sW[r * 18];
#pragma unroll
            for (int c = 0; c < 6; ++c) {
                acc[c] += vx * w[c];
                acc[c] += vy * w[6 + c];
                acc[c] += vz * w[12 + c];
            }
            // offset features (positions from global, L2-hot): rank 0 = self
            if (r >= 1) {
                float ox = posb[bg * 3 + 0] - qx;
                float oy = posb[bg * 3 + 1] - qy;
                float oz = posb[bg * 3 + 2] - qz;
                const float* w2 = &sW[(33 + (r - 1) * 3) * 6];
#pragma unroll
                for (int c = 0; c < 6; ++c) {
                    acc[c] += ox * w2[c];
                    acc[c] += oy * w2[6 + c];
                    acc[c] += oz * w2[12 + c];
                }
            }
        }
        // init_config features: slots [63..65]
#pragma unroll
        for (int k3 = 0; k3 < 3; ++k3) {
            const float* w3 = &sW[(63 + k3) * 6];
            float iv = sW[402 + k3];
#pragma unroll
            for (int c = 0; c < 6; ++c) acc[c] += iv * w3[c];
        }
        acc[0] += qx; acc[1] += qy; acc[2] += qz;

        float* op = out + (b * NPTS + q) * 6;
#pragma unroll
        for (int c = 0; c < 6; ++c) op[c] = acc[c];
    }
}

extern "C" void kernel_launch(void* const* d_in, const int* in_sizes, int n_in,
                              void* d_out, int out_size, void* d_ws, size_t ws_size,
                              hipStream_t stream) {
    (void)in_sizes; (void)n_in; (void)out_size; (void)d_ws; (void)ws_size;
    const float* pos   = (const float*)d_in[0];
    const float* vel   = (const float*)d_in[1];
    const float* initc = (const float*)d_in[2];
    const float* W1    = (const float*)d_in[3];
    const float* b1    = (const float*)d_in[4];
    const float* W2    = (const float*)d_in[5];
    const float* b2    = (const float*)d_in[6];
    const float* W3    = (const float*)d_in[7];
    const float* b3    = (const float*)d_in[8];
    float* out = (float*)d_out;

    knn_mlp<<<256, NTHR, 0, stream>>>(pos, vel, initc, W1, b1, W2, b2, W3, b3, out);
}

// Round 8
// 183.091 us; speedup vs baseline: 1.1528x; 1.1528x over previous
//
#include <hip/hip_runtime.h>

// B=2, N=8192, K=10, I=3, LEN_IN=66. All buffers f32.
// LOCKED correctness recipe (R8-R12, passed, absmax 0.0625):
//   sq  = fmaf(z,z, fmaf(y,y, rn(x*x)))          (asc FMA)
//   dot = fmaf(z,z', fmaf(y,y', rn(x*x')))       (asc FMA)
//   d2  = fmaf(-2,dot, rn(sq_q + sq_c))          (== single-rounded sub form)
//   selection: strict <, stable lowest-index-first (lexicographic (d2,idx))
// LOCKED code (R16/R19/R20 post-mortem): the R13 scan/flush/insert TEXT.
//   Every threshold-machinery edit (atomic publish, fminf tail, loop split)
//   regressed +19..39us via codegen effects my static model can't predict.
//   thr = d10 stale copy, TRIG=7, DEPTH=10 — do not touch.
// R21: geometry split. R13 runs 1 block(1024t)/CU = ONE barrier/convergence
//   domain; iid data => all 16 waves TRIG-flush at correlated times =>
//   correlated stalls, VALUBusy stuck at 70% with 30% issue-idle.
//   Split to 512 blocks x 512 threads: 32 queries x 16 slices per block
//   (slice = tid>>5, qq = tid&31; tid == slice*32+qq so merge indexing is
//   structurally unchanged). LDS/block = 32K ssq + 40K region ~= 74KB =>
//   2 INDEPENDENT blocks/CU (148KB < 160KB): same 16 waves/CU, but two
//   desynchronized flush/barrier domains fill each other's bubbles.
//   Per-lane scan work is bit-identical to R13 (same slice length 512,
//   same insert order => same stable top-11 => exact merge).
#define NPTS   8192
#define KNN    11
#define QPB    32          // queries per block (one per half-wave lane slot)
#define NTHR   512
#define NSLICE 16          // candidate slices (one per half-wave)
#define SLEN   (NPTS / NSLICE)   // 512
#define DEPTH  10          // per-lane push-buffer entries (R13 value)
#define TRIG   7           // flush when any lane cnt >= TRIG (4 pushes headroom)

__global__ __launch_bounds__(NTHR, 4) void knn_mlp(
    const float* __restrict__ pos,
    const float* __restrict__ vel,
    const float* __restrict__ initc,
    const float* __restrict__ W1,
    const float* __restrict__ b1,
    const float* __restrict__ W2,
    const float* __restrict__ b2,
    const float* __restrict__ W3,
    const float* __restrict__ b3,
    float* __restrict__ out) {

    // Phased LDS (72KB):
    //   phase-scan : [0,32K) ssq | [32K,72K) push region [k][tid] u64
    //   phase-fold : [32K, ...) fold scratch (4.3KB)
    //   phase-merge: [0,22K) pd f32 | [22K,44K) pi i32   (ssq/region dead)
    __shared__ __align__(16) char smem[32 * 1024 + NTHR * DEPTH * 8];
    __shared__ float sW[405];           // Weff[396] + bias[6] + init[3]

    float* ssq = (float*)smem;
    unsigned long long* region = (unsigned long long*)(smem + 32 * 1024);

    const int tid   = threadIdx.x;
    const int slice = tid >> 5;                 // 0..15 (one per half-wave)
    const int qq    = tid & 31;                 // query slot in block
    const int b     = blockIdx.x >> 8;          // 256 blocks per batch
    const int n0    = (blockIdx.x & 255) * QPB;
    const int q     = n0 + qq;

    const float* posb = pos + b * NPTS * 3;
    const float* velb = vel + b * NPTS * 3;

    // ---- phase 1a: per-point sq into LDS (LOCKED recipe)
    for (int a = tid; a < NPTS; a += NTHR) {
        float x = posb[a * 3 + 0];
        float y = posb[a * 3 + 1];
        float z = posb[a * 3 + 2];
        ssq[a] = __fmaf_rn(z, z, __fmaf_rn(y, y, __fmul_rn(x, x)));
    }
    // ---- phase 1b: fold stage 1 (scratch in region): W12 = W1@W2, b12 = b1@W2+b2
    float* sW12 = (float*)region;
    for (int e = tid; e < 66 * 16; e += NTHR) {
        int r = e >> 4, c = e & 15;
        float s = 0.f;
        for (int j = 0; j < 32; ++j) s += W1[r * 32 + j] * W2[j * 16 + c];
        sW12[e] = s;
    }
    if (tid < 16) {
        float s = b2[tid];
        for (int j = 0; j < 32; ++j) s += b1[j] * W2[j * 16 + tid];
        sW12[66 * 16 + tid] = s;
    }
    if (tid < 3) sW[402 + tid] = initc[b * 3 + tid];
    __syncthreads();
    // ---- fold stage 2: Weff = W12@W3, bias = b12@W3 + b3
    for (int e = tid; e < 66 * 6; e += NTHR) {
        int r = e / 6, c = e - r * 6;
        float s = 0.f;
        for (int j = 0; j < 16; ++j) s += sW12[r * 16 + j] * W3[j * 6 + c];
        sW[e] = s;
    }
    if (tid < 6) {
        float s = b3[tid];
        for (int j = 0; j < 16; ++j) s += sW12[66 * 16 + j] * W3[j * 6 + tid];
        sW[396 + tid] = s;
    }
    __syncthreads();   // fold scratch done -> region becomes push buffers

    const float qx = posb[q * 3 + 0];
    const float qy = posb[q * 3 + 1];
    const float qz = posb[q * 3 + 2];
    const float sqq = ssq[q];           // identical bits to locked recipe

    // Top-11 in NAMED SCALARS (forced register residency; R12 demoted arrays).
    float d0 = 3.0e38f, d1 = 3.0e38f, d2v = 3.0e38f, d3 = 3.0e38f, d4 = 3.0e38f,
          d5 = 3.0e38f, d6 = 3.0e38f, d7 = 3.0e38f, d8 = 3.0e38f, d9 = 3.0e38f,
          d10 = 3.0e38f;
    int   i0 = 0x7FFFFFFF, i1 = 0x7FFFFFFF, i2v = 0x7FFFFFFF, i3 = 0x7FFFFFFF,
          i4 = 0x7FFFFFFF, i5 = 0x7FFFFFFF, i6 = 0x7FFFFFFF, i7 = 0x7FFFFFFF,
          i8 = 0x7FFFFFFF, i9 = 0x7FFFFFFF, i10 = 0x7FFFFFFF;

    float thr = 3.0e38f;       // stale copy of d10; only over-buffers, never drops
    int cnt = 0;

    // Hand-unrolled stable insert (identical semantics to the array loop).
    auto insert = [&](float nd, int nj) {
        if (nd < d10) {
            bool c, cp;
            cp = nd < d9;  d10 = cp ? d9  : nd;             i10 = cp ? i9  : nj;             c = cp;
            cp = nd < d8;  d9  = cp ? d8  : (c ? nd : d9);  i9  = cp ? i8  : (c ? nj : i9);  c = cp;
            cp = nd < d7;  d8  = cp ? d7  : (c ? nd : d8);  i8  = cp ? i7  : (c ? nj : i8);  c = cp;
            cp = nd < d6;  d7  = cp ? d6  : (c ? nd : d7);  i7  = cp ? i6  : (c ? nj : i7);  c = cp;
            cp = nd < d5;  d6  = cp ? d5  : (c ? nd : d6);  i6  = cp ? i5  : (c ? nj : i6);  c = cp;
            cp = nd < d4;  d5  = cp ? d4  : (c ? nd : d5);  i5  = cp ? i4  : (c ? nj : i5);  c = cp;
            cp = nd < d3;  d4  = cp ? d3  : (c ? nd : d4);  i4  = cp ? i3  : (c ? nj : i4);  c = cp;
            cp = nd < d2v; d3  = cp ? d2v : (c ? nd : d3);  i3  = cp ? i2v : (c ? nj : i3);  c = cp;
            cp = nd < d1;  d2v = cp ? d1  : (c ? nd : d2v); i2v = cp ? i1  : (c ? nj : i2v); c = cp;
            cp = nd < d0;  d1  = cp ? d0  : (c ? nd : d1);  i1  = cp ? i0  : (c ? nj : i1);  c = cp;
            if (c) { d0 = nd; i0 = nj; }
        }
    };

    auto flush = [&]() {
#pragma unroll 1
        for (int k = 0; __any(k < cnt); ++k) {
            if (k < cnt) {
                unsigned long long e = region[k * NTHR + tid];  // [k][tid]: 2-way only
                float nd = __uint_as_float((unsigned)(e >> 32));
                int   nj = (int)(unsigned)(e & 0xFFFFFFFFull);
                insert(nd, nj);
            }
        }
        cnt = 0;
        thr = d10;
    };

    auto proc = [&](float cx, float cy, float cz, float sqc, int j) {
        float dot = __fmaf_rn(qz, cz, __fmaf_rn(qy, cy, __fmul_rn(qx, cx)));
        float dd  = __fmaf_rn(-2.0f, dot, __fadd_rn(sqq, sqc)); // == rn(s-2dot)
        if (dd < thr) {
            region[cnt * NTHR + tid] =
                (((unsigned long long)__float_as_uint(dd)) << 32) | (unsigned)j;
            ++cnt;
        }
    };

    // ---- scan: half-wave streams its 512-candidate slice from global
    // (L2-hot). EXACT R13 loop text; only `base` derivation differs.
    const int base = slice * SLEN;
    const float4* gp = (const float4*)(posb + base * 3);  // 3 float4 per 4 cands
    const float4* sp = (const float4*)(ssq + base);
#pragma unroll 1
    for (int m = 0; m < SLEN; m += 4) {
        int f = (m >> 2) * 3;
        float4 A = gp[f], Bv = gp[f + 1], C = gp[f + 2];
        float4 S = sp[m >> 2];
        int j = base + m;
        proc(A.x,  A.y,  A.z,  S.x, j + 0);
        proc(A.w,  Bv.x, Bv.y, S.y, j + 1);
        proc(Bv.z, Bv.w, C.x,  S.z, j + 2);
        proc(C.y,  C.z,  C.w,  S.w, j + 3);
        if (__any(cnt >= TRIG)) flush();                  // rare wave-uniform path
    }
    flush();

    __syncthreads();   // scans done -> smem becomes merge lists
    float* pd = (float*)smem;                       // [NTHR][11] f32
    int*   pi = (int*)(smem + NTHR * KNN * 4);      // [NTHR][11] i32
    {
        // tid == slice*32 + qq, so [tid][*] is already [slice][query] order.
        float* pw = pd + tid * KNN;
        int*   iw = pi + tid * KNN;
        pw[0] = d0;  pw[1] = d1;  pw[2] = d2v; pw[3] = d3;  pw[4] = d4;
        pw[5] = d5;  pw[6] = d6;  pw[7] = d7;  pw[8] = d8;  pw[9] = d9;
        pw[10] = d10;
        iw[0] = i0;  iw[1] = i1;  iw[2] = i2v; iw[3] = i3;  iw[4] = i4;
        iw[5] = i5;  iw[6] = i6;  iw[7] = i7;  iw[8] = i8;  iw[9] = i9;
        iw[10] = i10;
    }
    __syncthreads();

    if (tid < QPB) {
        // 16-way merge, lexicographic (d2, idx) == global stable top-11.
        int p[NSLICE]; float hd[NSLICE]; int hi[NSLICE];
#pragma unroll
        for (int s = 0; s < NSLICE; ++s) {
            p[s]  = 0;
            hd[s] = pd[(s * QPB + tid) * KNN];
            hi[s] = pi[(s * QPB + tid) * KNN];
        }
        float acc[6];
#pragma unroll
        for (int c = 0; c < 6; ++c) acc[c] = sW[396 + c];

        for (int r = 0; r < KNN; ++r) {
            float bd = 3.9e38f; int bi = 0x7FFFFFFF; int bs = 0;
#pragma unroll
            for (int s = 0; s < NSLICE; ++s) {
                bool better = (hd[s] < bd) || (hd[s] == bd && hi[s] < bi);
                bs = better ? s : bs;
                bi = better ? hi[s] : bi;
                bd = better ? hd[s] : bd;
            }
            {   // advance winning slice head
                int pp = ++p[bs];
                if (pp < KNN) {
                    hd[bs] = pd[(bs * QPB + tid) * KNN + pp];
                    hi[bs] = pi[(bs * QPB + tid) * KNN + pp];
                } else { hd[bs] = 3.9e38f; hi[bs] = 0x7FFFFFFF; }
            }

            int bg = ((unsigned)bi < (unsigned)NPTS) ? bi : 0;   // defensive

            // velocity features: slots [r*3 .. r*3+2]
            const float* vp = velb + bg * 3;
            float vx = vp[0], vy = vp[1], vz = vp[2];
            const float* w = &sW[r * 18];
#pragma unroll
            for (int c = 0; c < 6; ++c) {
                acc[c] += vx * w[c];
                acc[c] += vy * w[6 + c];
                acc[c] += vz * w[12 + c];
            }
            // offset features (positions from global, L2-hot): rank 0 = self
            if (r >= 1) {
                float ox = posb[bg * 3 + 0] - qx;
                float oy = posb[bg * 3 + 1] - qy;
                float oz = posb[bg * 3 + 2] - qz;
                const float* w2 = &sW[(33 + (r - 1) * 3) * 6];
#pragma unroll
                for (int c = 0; c < 6; ++c) {
                    acc[c] += ox * w2[c];
                    acc[c] += oy * w2[6 + c];
                    acc[c] += oz * w2[12 + c];
                }
            }
        }
        // init_config features: slots [63..65]
#pragma unroll
        for (int k3 = 0; k3 < 3; ++k3) {
            const float* w3 = &sW[(63 + k3) * 6];
            float iv = sW[402 + k3];
#pragma unroll
            for (int c = 0; c < 6; ++c) acc[c] += iv * w3[c];
        }
        acc[0] += qx; acc[1] += qy; acc[2] += qz;

        float* op = out + (b * NPTS + q) * 6;
#pragma unroll
        for (int c = 0; c < 6; ++c) op[c] = acc[c];
    }
}

extern "C" void kernel_launch(void* const* d_in, const int* in_sizes, int n_in,
                              void* d_out, int out_size, void* d_ws, size_t ws_size,
                              hipStream_t stream) {
    (void)in_sizes; (void)n_in; (void)out_size; (void)d_ws; (void)ws_size;
    const float* pos   = (const float*)d_in[0];
    const float* vel   = (const float*)d_in[1];
    const float* initc = (const float*)d_in[2];
    const float* W1    = (const float*)d_in[3];
    const float* b1    = (const float*)d_in[4];
    const float* W2    = (const float*)d_in[5];
    const float* b2    = (const float*)d_in[6];
    const float* W3    = (const float*)d_in[7];
    const float* b3    = (const float*)d_in[8];
    float* out = (float*)d_out;

    knn_mlp<<<512, NTHR, 0, stream>>>(pos, vel, initc, W1, b1, W2, b2, W3, b3, out);
}

// Round 10
// 174.872 us; speedup vs baseline: 1.2070x; 1.0470x over previous
//
#include <hip/hip_runtime.h>

// B=2, N=8192, K=10, I=3, LEN_IN=66. All buffers f32.
// LOCKED correctness recipe (R8-R12, passed, absmax 0.0625):
//   sq  = fmaf(z,z, fmaf(y,y, rn(x*x)))          (asc FMA)
//   dot = fmaf(z,z', fmaf(y,y', rn(x*x')))       (asc FMA)
//   d2  = fmaf(-2,dot, rn(sq_q + sq_c))          (== single-rounded sub form)
//   selection: strict <, stable lowest-index-first (lexicographic (d2,idx))
// R22/R23: bit-exact restore of the R13 champion (117.4us rocprof, measured
//   twice). R22's bench died at container acquire — this exact source has
//   run clean before, so the failure is infra by construction (3rd
//   kernel-independent acquire fault this session). Resubmitting verbatim.
//   Experiment matrix closed out:
//   - R14/R15 scheduling+pipelining: neutral (compiler sinks unpinned
//     prefetch; sched_barrier only constrains).
//   - R16/R19/R20 shared thresholds (atomic, tail-only, rendezvous):
//     +19..39us — the TRIG-flush branch-skip is codegen-fragile; any edit
//     near it risks if-conversion of the ~115-inst flush body into the
//     128-iteration scan path.
//   - R21 geometry split (512x512, 2 blocks/CU): -8us; occupancy DROPPED
//     (33.7% vs 38.3%), VALUBusy flat, +66% bank conflicts.
//   Structural floor: VALU-busy ~197K/281K cyc; insert chain ~125K of it,
//   wave-max-amplified (Σ wave-max(cnt) ~200+ iterations x 154 cyc) and
//   irreducible under the lane=query mapping (a lane's buffered entries
//   can only be consumed by that lane). Remaining levers all falsified.
#define NPTS   8192
#define KNN    11
#define QPB    64          // queries per block (one per lane)
#define NTHR   1024
#define NSLICE 16          // candidate slices (one per wave)
#define SLEN   (NPTS / NSLICE)   // 512
#define DEPTH  10          // per-lane push-buffer entries
#define TRIG   7           // flush when any lane cnt >= TRIG (4 pushes headroom)

__global__ __launch_bounds__(NTHR, 4) void knn_mlp(
    const float* __restrict__ pos,
    const float* __restrict__ vel,
    const float* __restrict__ initc,
    const float* __restrict__ W1,
    const float* __restrict__ b1,
    const float* __restrict__ W2,
    const float* __restrict__ b2,
    const float* __restrict__ W3,
    const float* __restrict__ b3,
    float* __restrict__ out) {

    // Phased LDS (112KB):
    //   phase-scan : [0,32K) ssq | [32K,112K) push region [k][tid] u64
    //   phase-fold : [32K, ...) fold scratch (4.3KB)
    //   phase-merge: [0,45K) pd f32 | [45K,90K) pi i32   (ssq/region dead)
    __shared__ __align__(16) char smem[32 * 1024 + NTHR * DEPTH * 8];
    __shared__ float sW[405];           // Weff[396] + bias[6] + init[3]

    float* ssq = (float*)smem;
    unsigned long long* region = (unsigned long long*)(smem + 32 * 1024);

    const int tid  = threadIdx.x;
    const int lane = tid & 63;
    const int wave = tid >> 6;
    const int b    = blockIdx.x >> 7;           // 128 blocks per batch
    const int n0   = (blockIdx.x & 127) * QPB;
    const int q    = n0 + lane;

    const float* posb = pos + b * NPTS * 3;
    const float* velb = vel + b * NPTS * 3;

    // ---- phase 1a: per-point sq into LDS (LOCKED recipe)
    for (int a = tid; a < NPTS; a += NTHR) {
        float x = posb[a * 3 + 0];
        float y = posb[a * 3 + 1];
        float z = posb[a * 3 + 2];
        ssq[a] = __fmaf_rn(z, z, __fmaf_rn(y, y, __fmul_rn(x, x)));
    }
    // ---- phase 1b: fold stage 1 (scratch in region): W12 = W1@W2, b12 = b1@W2+b2
    float* sW12 = (float*)region;
    for (int e = tid; e < 66 * 16; e += NTHR) {
        int r = e >> 4, c = e & 15;
        float s = 0.f;
        for (int j = 0; j < 32; ++j) s += W1[r * 32 + j] * W2[j * 16 + c];
        sW12[e] = s;
    }
    if (tid < 16) {
        float s = b2[tid];
        for (int j = 0; j < 32; ++j) s += b1[j] * W2[j * 16 + tid];
        sW12[66 * 16 + tid] = s;
    }
    if (tid < 3) sW[402 + tid] = initc[b * 3 + tid];
    __syncthreads();
    // ---- fold stage 2: Weff = W12@W3, bias = b12@W3 + b3
    for (int e = tid; e < 66 * 6; e += NTHR) {
        int r = e / 6, c = e - r * 6;
        float s = 0.f;
        for (int j = 0; j < 16; ++j) s += sW12[r * 16 + j] * W3[j * 6 + c];
        sW[e] = s;
    }
    if (tid < 6) {
        float s = b3[tid];
        for (int j = 0; j < 16; ++j) s += sW12[66 * 16 + j] * W3[j * 6 + tid];
        sW[396 + tid] = s;
    }
    __syncthreads();   // fold scratch done -> region becomes push buffers

    const float qx = posb[q * 3 + 0];
    const float qy = posb[q * 3 + 1];
    const float qz = posb[q * 3 + 2];
    const float sqq = ssq[q];           // identical bits to locked recipe

    // Top-11 in NAMED SCALARS (forced register residency; R12 demoted arrays).
    float d0 = 3.0e38f, d1 = 3.0e38f, d2v = 3.0e38f, d3 = 3.0e38f, d4 = 3.0e38f,
          d5 = 3.0e38f, d6 = 3.0e38f, d7 = 3.0e38f, d8 = 3.0e38f, d9 = 3.0e38f,
          d10 = 3.0e38f;
    int   i0 = 0x7FFFFFFF, i1 = 0x7FFFFFFF, i2v = 0x7FFFFFFF, i3 = 0x7FFFFFFF,
          i4 = 0x7FFFFFFF, i5 = 0x7FFFFFFF, i6 = 0x7FFFFFFF, i7 = 0x7FFFFFFF,
          i8 = 0x7FFFFFFF, i9 = 0x7FFFFFFF, i10 = 0x7FFFFFFF;

    float thr = 3.0e38f;       // stale copy of d10; only over-buffers, never drops
    int cnt = 0;

    // Hand-unrolled stable insert (identical semantics to the array loop).
    auto insert = [&](float nd, int nj) {
        if (nd < d10) {
            bool c, cp;
            cp = nd < d9;  d10 = cp ? d9  : nd;             i10 = cp ? i9  : nj;             c = cp;
            cp = nd < d8;  d9  = cp ? d8  : (c ? nd : d9);  i9  = cp ? i8  : (c ? nj : i9);  c = cp;
            cp = nd < d7;  d8  = cp ? d7  : (c ? nd : d8);  i8  = cp ? i7  : (c ? nj : i8);  c = cp;
            cp = nd < d6;  d7  = cp ? d6  : (c ? nd : d7);  i7  = cp ? i6  : (c ? nj : i7);  c = cp;
            cp = nd < d5;  d6  = cp ? d5  : (c ? nd : d6);  i6  = cp ? i5  : (c ? nj : i6);  c = cp;
            cp = nd < d4;  d5  = cp ? d4  : (c ? nd : d5);  i5  = cp ? i4  : (c ? nj : i5);  c = cp;
            cp = nd < d3;  d4  = cp ? d3  : (c ? nd : d4);  i4  = cp ? i3  : (c ? nj : i4);  c = cp;
            cp = nd < d2v; d3  = cp ? d2v : (c ? nd : d3);  i3  = cp ? i2v : (c ? nj : i3);  c = cp;
            cp = nd < d1;  d2v = cp ? d1  : (c ? nd : d2v); i2v = cp ? i1  : (c ? nj : i2v); c = cp;
            cp = nd < d0;  d1  = cp ? d0  : (c ? nd : d1);  i1  = cp ? i0  : (c ? nj : i1);  c = cp;
            if (c) { d0 = nd; i0 = nj; }
        }
    };

    auto flush = [&]() {
#pragma unroll 1
        for (int k = 0; __any(k < cnt); ++k) {
            if (k < cnt) {
                unsigned long long e = region[k * NTHR + tid];  // [k][tid]: 2-way only
                float nd = __uint_as_float((unsigned)(e >> 32));
                int   nj = (int)(unsigned)(e & 0xFFFFFFFFull);
                insert(nd, nj);
            }
        }
        cnt = 0;
        thr = d10;
    };

    auto proc = [&](float cx, float cy, float cz, float sqc, int j) {
        float dot = __fmaf_rn(qz, cz, __fmaf_rn(qy, cy, __fmul_rn(qx, cx)));
        float dd  = __fmaf_rn(-2.0f, dot, __fadd_rn(sqq, sqc)); // == rn(s-2dot)
        if (dd < thr) {
            region[cnt * NTHR + tid] =
                (((unsigned long long)__float_as_uint(dd)) << 32) | (unsigned)j;
            ++cnt;
        }
    };

    // ---- scan: wave streams its 512-candidate slice from global (L2-hot).
    const int base = wave * SLEN;
    const float4* gp = (const float4*)(posb + base * 3);  // 3 float4 per 4 cands
    const float4* sp = (const float4*)(ssq + base);
#pragma unroll 1
    for (int m = 0; m < SLEN; m += 4) {
        int f = (m >> 2) * 3;
        float4 A = gp[f], Bv = gp[f + 1], C = gp[f + 2];
        float4 S = sp[m >> 2];
        int j = base + m;
        proc(A.x,  A.y,  A.z,  S.x, j + 0);
        proc(A.w,  Bv.x, Bv.y, S.y, j + 1);
        proc(Bv.z, Bv.w, C.x,  S.z, j + 2);
        proc(C.y,  C.z,  C.w,  S.w, j + 3);
        if (__any(cnt >= TRIG)) flush();                  // rare wave-uniform path
    }
    flush();

    __syncthreads();   // scans done -> smem becomes merge lists
    float* pd = (float*)smem;                       // [NTHR][11] f32
    int*   pi = (int*)(smem + NTHR * KNN * 4);      // [NTHR][11] i32
    {
        float* pw = pd + tid * KNN;
        int*   iw = pi + tid * KNN;
        pw[0] = d0;  pw[1] = d1;  pw[2] = d2v; pw[3] = d3;  pw[4] = d4;
        pw[5] = d5;  pw[6] = d6;  pw[7] = d7;  pw[8] = d8;  pw[9] = d9;
        pw[10] = d10;
        iw[0] = i0;  iw[1] = i1;  iw[2] = i2v; iw[3] = i3;  iw[4] = i4;
        iw[5] = i5;  iw[6] = i6;  iw[7] = i7;  iw[8] = i8;  iw[9] = i9;
        iw[10] = i10;
    }
    __syncthreads();

    if (tid < QPB) {
        // 16-way merge, lexicographic (d2, idx) == global stable top-11.
        int p[NSLICE]; float hd[NSLICE]; int hi[NSLICE];
#pragma unroll
        for (int s = 0; s < NSLICE; ++s) {
            p[s]  = 0;
            hd[s] = pd[(s * 64 + tid) * KNN];
            hi[s] = pi[(s * 64 + tid) * KNN];
        }
        float acc[6];
#pragma unroll
        for (int c = 0; c < 6; ++c) acc[c] = sW[396 + c];

        for (int r = 0; r < KNN; ++r) {
            float bd = 3.9e38f; int bi = 0x7FFFFFFF; int bs = 0;
#pragma unroll
            for (int s = 0; s < NSLICE; ++s) {
                bool better = (hd[s] < bd) || (hd[s] == bd && hi[s] < bi);
                bs = better ? s : bs;
                bi = better ? hi[s] : bi;
                bd = better ? hd[s] : bd;
            }
            {   // advance winning slice head
                int pp = ++p[bs];
                if (pp < KNN) {
                    hd[bs] = pd[(bs * 64 + tid) * KNN + pp];
                    hi[bs] = pi[(bs * 64 + tid) * KNN + pp];
                } else { hd[bs] = 3.9e38f; hi[bs] = 0x7FFFFFFF; }
            }

            int bg = ((unsigned)bi < (unsigned)NPTS) ? bi : 0;   // defensive

            // velocity features: slots [r*3 .. r*3+2]
            const float* vp = velb + bg * 3;
            float vx = vp[0], vy = vp[1], vz = vp[2];
            const float* w = &sW[r * 18];
#pragma unroll
            for (int c = 0; c < 6; ++c) {
                acc[c] += vx * w[c];
                acc[c] += vy * w[6 + c];
                acc[c] += vz * w[12 + c];
            }
            // offset features (positions from global, L2-hot): rank 0 = self
            if (r >= 1) {
                float ox = posb[bg * 3 + 0] - qx;
                float oy = posb[bg * 3 + 1] - qy;
                float oz = posb[bg * 3 + 2] - qz;
                const float* w2 = &sW[(33 + (r - 1) * 3) * 6];
#pragma unroll
                for (int c = 0; c < 6; ++c) {
                    acc[c] += ox * w2[c];
                    acc[c] += oy * w2[6 + c];
                    acc[c] += oz * w2[12 + c];
                }
            }
        }
        // init_config features: slots [63..65]
#pragma unroll
        for (int k3 = 0; k3 < 3; ++k3) {
            const float* w3 = &sW[(63 + k3) * 6];
            float iv = sW[402 + k3];
#pragma unroll
            for (int c = 0; c < 6; ++c) acc[c] += iv * w3[c];
        }
        acc[0] += qx; acc[1] += qy; acc[2] += qz;

        float* op = out + (b * NPTS + q) * 6;
#pragma unroll
        for (int c = 0; c < 6; ++c) op[c] = acc[c];
    }
}

extern "C" void kernel_launch(void* const* d_in, const int* in_sizes, int n_in,
                              void* d_out, int out_size, void* d_ws, size_t ws_size,
                              hipStream_t stream) {
    (void)in_sizes; (void)n_in; (void)out_size; (void)d_ws; (void)ws_size;
    const float* pos   = (const float*)d_in[0];
    const float* vel   = (const float*)d_in[1];
    const float* initc = (const float*)d_in[2];
    const float* W1    = (const float*)d_in[3];
    const float* b1    = (const float*)d_in[4];
    const float* W2    = (const float*)d_in[5];
    const float* b2    = (const float*)d_in[6];
    const float* W3    = (const float*)d_in[7];
    const float* b3    = (const float*)d_in[8];
    float* out = (float*)d_out;

    knn_mlp<<<256, NTHR, 0, stream>>>(pos, vel, initc, W1, b1, W2, b2, W3, b3, out);
}